// Round 1
// baseline (467.916 us; speedup 1.0000x reference)
//
#include <hip/hip_runtime.h>
#include <math.h>

#define KDEG 64

struct ZTab {
    float z0r[KDEG], z0i[KDEG], z1r[KDEG], z1i[KDEG];
    float scale;
};

// One wave (64 lanes) per row. Lane j evaluates the polynomial at z0[j] and
// z1[j] via Horner in strict numpy-complex64 rounding order (no fma).
__global__ __launch_bounds__(256) void decoder_kernel(
    const float* __restrict__ xr, const float* __restrict__ xi,
    float* __restrict__ out, ZTab zt)
{
    const int lane = (int)(threadIdx.x & 63u);
    int row = ((int)blockIdx.x * (int)blockDim.x + (int)threadIdx.x) >> 6;
    // row is wave-uniform; tell the compiler so coefficient loads scalarize.
    row = __builtin_amdgcn_readfirstlane(row);

    const float* __restrict__ rr = xr + (size_t)row * (KDEG + 1);
    const float* __restrict__ ri = xi + (size_t)row * (KDEG + 1);

    const float z0r = zt.z0r[lane], z0i = zt.z0i[lane];
    const float z1r = zt.z1r[lane], z1i = zt.z1i[lane];

    // init = x[:, 0] broadcast
    float a0r = rr[0], a0i = ri[0];
    float a1r = a0r,  a1i = a0i;

#pragma unroll
    for (int i = 1; i <= KDEG; ++i) {
        const float cr = rr[i];
        const float ci = ri[i];
        // res = res*z + c, numpy complex64 op order: (ar*br - ai*bi), (ar*bi + ai*br)
        float t0r = __fadd_rn(__fsub_rn(__fmul_rn(a0r, z0r), __fmul_rn(a0i, z0i)), cr);
        float t0i = __fadd_rn(__fadd_rn(__fmul_rn(a0r, z0i), __fmul_rn(a0i, z0r)), ci);
        float t1r = __fadd_rn(__fsub_rn(__fmul_rn(a1r, z1r), __fmul_rn(a1i, z1i)), cr);
        float t1i = __fadd_rn(__fadd_rn(__fmul_rn(a1r, z1i), __fmul_rn(a1i, z1r)), ci);
        a0r = t0r; a0i = t0i;
        a1r = t1r; a1i = t1i;
    }

    // |res| matching glibc hypotf: (float)sqrt((double)a*a + (double)b*b)
    // (float->double squares are exact; one double rounding on the sum; IEEE
    //  double sqrt; final round to float — identical sequence to glibc.)
    float h0 = (float)sqrt((double)a0r * (double)a0r + (double)a0i * (double)a0i);
    float h1 = (float)sqrt((double)a1r * (double)a1r + (double)a1i * (double)a1i);

    out[(size_t)row * KDEG + lane] = (__fmul_rn(zt.scale, h0) >= h1) ? 1.0f : 0.0f;
}

extern "C" void kernel_launch(void* const* d_in, const int* in_sizes, int n_in,
                              void* d_out, int out_size, void* d_ws, size_t ws_size,
                              hipStream_t stream)
{
    const float* xr = (const float*)d_in[0];
    const float* xi = (const float*)d_in[1];
    float* out = (float*)d_out;

    const int B = in_sizes[0] / (KDEG + 1);  // 262144

    // Host-side constant table, replicating numpy's float64 math exactly
    // (same glibc libm as the reference environment), then rounding to f32.
    ZTab zt;
    const double r = sqrt(1.0 + sin(M_PI / (double)KDEG));
    const double inv_r = 1.0 / r;
    for (int j = 0; j < KDEG; ++j) {
        double ang = (2.0 * M_PI) * (double)j / (double)KDEG;  // ((2π)*j)/K, numpy order
        double c = cos(ang), s = sin(ang);
        zt.z0r[j] = (float)(inv_r * c);
        zt.z0i[j] = (float)(inv_r * s);
        zt.z1r[j] = (float)(r * c);
        zt.z1i[j] = (float)(r * s);
    }
    zt.scale = (float)pow(r, (double)KDEG);

    // One wave per row, 4 rows per 256-thread block.
    const int rows_per_block = 4;
    const int grid = (B + rows_per_block - 1) / rows_per_block;
    decoder_kernel<<<grid, 256, 0, stream>>>(xr, xi, out, zt);
}